// Round 11
// baseline (607.972 us; speedup 1.0000x reference)
//
#include <hip/hip_runtime.h>

#define NSs 100000
#define NIi 20000
#define DD  128
#define E1e 600000
#define E2e 500000

// bucket/scan geometry: 256 dsts per bucket
#define NB_R 79                      // ceil(20000/256)
#define NB_V 391                     // ceil(100000/256)
#define NB_P 391
#define NB_ALL (NB_R + NB_V + NB_P)  // 861; seg bounds 79 / 470
#define TILE 8192                    // edges per binB block

typedef __attribute__((ext_vector_type(8))) __bf16 bf16x8;
typedef __attribute__((ext_vector_type(4))) __bf16 bf16x4;
typedef __attribute__((ext_vector_type(4))) float  floatx4;

__device__ __forceinline__ void async_copy16(void* lds, const void* gsrc)
{
    __builtin_amdgcn_global_load_lds(
        (const __attribute__((address_space(1))) void*)gsrc,
        (__attribute__((address_space(3))) void*)lds, 16, 0, 0);
}

__device__ __forceinline__ floatx4 cvt4(bf16x4 v)
{
    return (floatx4){ (float)v.x, (float)v.y, (float)v.z, (float)v.w };
}

// Swizzled-row addressing: 16B chunk c of row r lives at chunk c ^ (r&15).
__device__ __forceinline__ const char* swz_addr(
    const __bf16* tab, int r, int c16, int c8)
{
    return (const char*)tab + (size_t)r * 256 + (((c16 ^ (r & 15)) << 4) | c8);
}

// ===========================================================================
// prep1: fused one-shot conversions (weights + both node tables) AND the
// 3-relation histogram.
// ===========================================================================
__global__ __launch_bounds__(256) void prep1(
    const float* __restrict__ Wa, const float* __restrict__ Wb,
    const float* __restrict__ Wc, const float* __restrict__ Wd,
    const float* __restrict__ We, __bf16* __restrict__ wbf,
    const float* __restrict__ xs_in, __bf16* __restrict__ xsb,
    const float* __restrict__ xi_in, __bf16* __restrict__ xib,
    const int* __restrict__ rd, const int* __restrict__ vd,
    const int* __restrict__ pd,
    int* __restrict__ cr, int* __restrict__ cv, int* __restrict__ cp,
    int wblocks, int sblocks, int iblocks)
{
    int b = blockIdx.x;
    int cvtb = wblocks + sblocks + iblocks;
    if (b < cvtb) {
        if (b < wblocks) {
            int i = b * 256 + threadIdx.x;
            const float* srcs[5] = {Wa, Wb, Wc, Wd, We};
            wbf[i] = (__bf16)srcs[i >> 15][i & 32767];
            return;
        }
        const float* in; __bf16* out; int i; int M;
        if (b < wblocks + sblocks) {
            in = xs_in; out = xsb; M = NSs;
            i = (b - wblocks) * 256 + threadIdx.x;
        } else {
            in = xi_in; out = xib; M = NIi;
            i = (b - wblocks - sblocks) * 256 + threadIdx.x;
        }
        if (i >= M * 16) return;
        int r = i >> 4, c = i & 15;
        const float* p = in + (size_t)r * DD + c * 8;
        floatx4 a = *(const floatx4*)p;
        floatx4 d = *(const floatx4*)(p + 4);
        bf16x8 o = { (__bf16)a.x, (__bf16)a.y, (__bf16)a.z, (__bf16)a.w,
                     (__bf16)d.x, (__bf16)d.y, (__bf16)d.z, (__bf16)d.w };
        *(bf16x8*)((char*)out + (size_t)r * 256 + ((c ^ (r & 15)) << 4)) = o;
        return;
    }
    long i = (long)(b - cvtb) * 256 + threadIdx.x;
    if (i < E1e)                 atomicAdd(cr + rd[i], 1);
    else if (i < 2L * E1e)       atomicAdd(cv + vd[i - E1e], 1);
    else if (i < 2L * E1e + E2e) atomicAdd(cp + pd[i - 2L * E1e], 1);
}

// ===========================================================================
// Ordered CSR offsets.
// ===========================================================================
__global__ __launch_bounds__(256) void scanA(
    const int* __restrict__ cr, const int* __restrict__ cv,
    const int* __restrict__ cp,
    int* __restrict__ sr, int* __restrict__ sv, int* __restrict__ sp,
    int* __restrict__ bsum)
{
    int b = blockIdx.x;
    const int* cnt; int* start; int n; int i;
    if (b < NB_R)      { cnt = cr; start = sr; n = NIi; i = b * 256; }
    else if (b < NB_R + NB_V) { cnt = cv; start = sv; n = NSs; i = (b - NB_R) * 256; }
    else               { cnt = cp; start = sp; n = NSs; i = (b - NB_R - NB_V) * 256; }
    int tid = threadIdx.x;
    i += tid;
    int lane = tid & 63, w = tid >> 6;
    int c = (i < n) ? cnt[i] : 0;
    int sum = c;
#pragma unroll
    for (int o = 1; o < 64; o <<= 1) {
        int u = __shfl_up(sum, o, 64);
        if (lane >= o) sum += u;
    }
    __shared__ int wsum[4];
    if (lane == 63) wsum[w] = sum;
    __syncthreads();
    int wofs = 0;
    for (int k = 0; k < 4; ++k) if (k < w) wofs += wsum[k];
    if (i < n) start[i] = wofs + sum - c;          // block-local exclusive
    if (tid == 0) bsum[b] = wsum[0] + wsum[1] + wsum[2] + wsum[3];
}

// scanB: one block, segmented exclusive scan of bsum[861] -> btick & bstart.
__global__ __launch_bounds__(1024) void scanB(
    const int* __restrict__ bsum,
    int* __restrict__ btick, int* __restrict__ bstart)
{
    int tid = threadIdx.x;
    int v = (tid < NB_ALL) ? bsum[tid] : 0;
    int lane = tid & 63, w = tid >> 6;       // 16 waves
    int s = v;
#pragma unroll
    for (int o = 1; o < 64; o <<= 1) {
        int u = __shfl_up(s, o, 64);
        if (lane >= o) s += u;
    }
    __shared__ int ws[16];
    if (lane == 63) ws[w] = s;
    __syncthreads();
    int wofs = 0;
    for (int k = 0; k < 16; ++k) if (k < w) wofs += ws[k];
    int excl = wofs + s - v;                 // global exclusive scan
    __shared__ int segbase[3];
    if (tid == 0)      segbase[0] = 0;
    if (tid == NB_R)   segbase[1] = excl;
    if (tid == NB_R + NB_V) segbase[2] = excl;
    __syncthreads();
    if (tid < NB_ALL) {
        int sb = (tid < NB_R) ? segbase[0]
               : (tid < NB_R + NB_V) ? segbase[1] : segbase[2];
        int val = excl - sb;                 // relation-local bucket start
        btick[tid]  = val;
        bstart[tid] = val;
    }
}

// ===========================================================================
// scanC + binB: LDS-histogram radix binning (block-level bucket reservation).
// ===========================================================================
__global__ __launch_bounds__(256) void scanCbinB(
    int* __restrict__ sr, int* __restrict__ fr,
    int* __restrict__ sv, int* __restrict__ fv,
    int* __restrict__ sp, int* __restrict__ fp,
    const int* __restrict__ bstart, int* __restrict__ btick,
    const int* __restrict__ rs, const int* __restrict__ rd,
    const int* __restrict__ vs, const int* __restrict__ vd,
    const int* __restrict__ ps, const int* __restrict__ pd,
    unsigned int* __restrict__ tr, unsigned int* __restrict__ tv,
    unsigned int* __restrict__ tp,
    int nbr_blocks, int nbv_blocks)
{
    int b = blockIdx.x;
    if (b < NB_ALL) {
        int* start; int* fill; int n; int i;
        if (b < NB_R)      { start = sr; fill = fr; n = NIi; i = b * 256; }
        else if (b < NB_R + NB_V) { start = sv; fill = fv; n = NSs; i = (b - NB_R) * 256; }
        else               { start = sp; fill = fp; n = NSs; i = (b - NB_R - NB_V) * 256; }
        i += threadIdx.x;
        if (i < n) {
            int st = start[i] + bstart[b];
            start[i] = st;
            fill[i]  = st;
        }
        return;
    }
    __shared__ int lhist[NB_V];              // 391 max buckets per relation
    __shared__ int lbase[NB_V];
    int bb2 = b - NB_ALL;
    const int* src; const int* dst; unsigned int* tmp;
    long e0; long ecnt; int tickofs; int nbkt;
    if (bb2 < nbr_blocks) {
        src = rs; dst = rd; tmp = tr; e0 = (long)bb2 * TILE; ecnt = E1e;
        tickofs = 0; nbkt = NB_R;
    } else if (bb2 < nbr_blocks + nbv_blocks) {
        src = vs; dst = vd; tmp = tv; e0 = (long)(bb2 - nbr_blocks) * TILE;
        ecnt = E1e; tickofs = NB_R; nbkt = NB_V;
    } else {
        src = ps; dst = pd; tmp = tp;
        e0 = (long)(bb2 - nbr_blocks - nbv_blocks) * TILE; ecnt = E2e;
        tickofs = NB_R + NB_V; nbkt = NB_P;
    }
    int tid = threadIdx.x;
    for (int i = tid; i < nbkt; i += 256) lhist[i] = 0;
    __syncthreads();
    long e1 = e0 + TILE; if (e1 > ecnt) e1 = ecnt;
    for (long e = e0 + tid; e < e1; e += 256)
        atomicAdd(&lhist[dst[e] >> 8], 1);
    __syncthreads();
    for (int i = tid; i < nbkt; i += 256) {
        int c = lhist[i];
        lbase[i] = c ? atomicAdd(btick + tickofs + i, c) : 0;
        lhist[i] = 0;                        // reuse as running offset
    }
    __syncthreads();
    for (long e = e0 + tid; e < e1; e += 256) {
        int d = dst[e];
        int bk = d >> 8;
        int pos = lbase[bk] + atomicAdd(&lhist[bk], 1);
        tmp[pos] = (unsigned int)src[e] | ((unsigned int)(d & 255) << 17);
    }
}

// binC: one block per bucket; scatter into the bucket's CONTIGUOUS eidx
// region (L2-resident), fill atomics in a 1 KB dst window.
__global__ __launch_bounds__(256) void binC(
    const int* __restrict__ bstart, const int* __restrict__ btick,
    const unsigned int* __restrict__ tr, const unsigned int* __restrict__ tv,
    const unsigned int* __restrict__ tp,
    int* __restrict__ fr, int* __restrict__ fv, int* __restrict__ fp,
    int* __restrict__ er, int* __restrict__ ev, int* __restrict__ ep)
{
    int b = blockIdx.x;
    const unsigned int* tmp; int* fill; int* eidx; int dstbase;
    if (b < NB_R)      { tmp = tr; fill = fr; eidx = er; dstbase = b << 8; }
    else if (b < NB_R + NB_V) { tmp = tv; fill = fv; eidx = ev; dstbase = (b - NB_R) << 8; }
    else               { tmp = tp; fill = fp; eidx = ep; dstbase = (b - NB_R - NB_V) << 8; }
    int bs = bstart[b], be = btick[b];       // btick == bucket end after binB
    for (int e = bs + threadIdx.x; e < be; e += 256) {
        unsigned int v = tmp[e];
        int src = (int)(v & 0x1FFFFu);
        int dst = dstbase | (int)(v >> 17);
        int pos = atomicAdd(fill + dst, 1);
        eidx[pos] = src;
    }
}

// ===========================================================================
// Per-row gather into LDS (16/8/4/2/1 ladder; bit-identical per-row order).
// ===========================================================================
__device__ __forceinline__ void gather_row_lds(
    const __bf16* __restrict__ x,
    const int* __restrict__ eidx,
    int s0, int s1, bool mean,
    __bf16* __restrict__ Abase, int lrow, int sub)
{
    int c16 = sub >> 1;
    int c8  = (sub & 1) << 3;
    floatx4 acc = {0.f, 0.f, 0.f, 0.f};
    int base = s0;
    while (base < s1) {
        int chunk = s1 - base; if (chunk > 32) chunk = 32;
        int my_e = eidx[base + (sub < chunk ? sub : chunk - 1)];
        int j = 0;
        for (; j + 16 <= chunk; j += 16) {
            bf16x4 v[16];
#pragma unroll
            for (int k = 0; k < 16; ++k) {
                int rr = __shfl(my_e, j + k, 32);
                v[k] = *(const bf16x4*)swz_addr(x, rr, c16, c8);
            }
            floatx4 t0 = (cvt4(v[0]) + cvt4(v[1])) + (cvt4(v[2]) + cvt4(v[3]));
            floatx4 t1 = (cvt4(v[4]) + cvt4(v[5])) + (cvt4(v[6]) + cvt4(v[7]));
            floatx4 t2 = (cvt4(v[8]) + cvt4(v[9])) + (cvt4(v[10]) + cvt4(v[11]));
            floatx4 t3 = (cvt4(v[12]) + cvt4(v[13])) + (cvt4(v[14]) + cvt4(v[15]));
            acc += (t0 + t1) + (t2 + t3);
        }
        if (j + 8 <= chunk) {
            bf16x4 v[8];
#pragma unroll
            for (int k = 0; k < 8; ++k) {
                int rr = __shfl(my_e, j + k, 32);
                v[k] = *(const bf16x4*)swz_addr(x, rr, c16, c8);
            }
            acc += ((cvt4(v[0]) + cvt4(v[1])) + (cvt4(v[2]) + cvt4(v[3]))) +
                   ((cvt4(v[4]) + cvt4(v[5])) + (cvt4(v[6]) + cvt4(v[7])));
            j += 8;
        }
        if (j + 4 <= chunk) {
            bf16x4 v[4];
#pragma unroll
            for (int k = 0; k < 4; ++k) {
                int rr = __shfl(my_e, j + k, 32);
                v[k] = *(const bf16x4*)swz_addr(x, rr, c16, c8);
            }
            acc += (cvt4(v[0]) + cvt4(v[1])) + (cvt4(v[2]) + cvt4(v[3]));
            j += 4;
        }
        if (j + 2 <= chunk) {
            int r0 = __shfl(my_e, j + 0, 32);
            int r1 = __shfl(my_e, j + 1, 32);
            bf16x4 v0 = *(const bf16x4*)swz_addr(x, r0, c16, c8);
            bf16x4 v1 = *(const bf16x4*)swz_addr(x, r1, c16, c8);
            acc += cvt4(v0) + cvt4(v1);
            j += 2;
        }
        if (j < chunk) {
            int r0 = __shfl(my_e, j, 32);
            acc += cvt4(*(const bf16x4*)swz_addr(x, r0, c16, c8));
        }
        base += chunk;
    }
    if (mean) {
        int deg = s1 - s0;
        float inv = 1.0f / (float)(deg > 1 ? deg : 1);
        acc.x *= inv; acc.y *= inv; acc.z *= inv; acc.w *= inv;
    }
    bf16x4 o = { (__bf16)acc.x, (__bf16)acc.y, (__bf16)acc.z, (__bf16)acc.w };
    *(bf16x4*)((char*)Abase + lrow * 256 + (((c16 ^ (lrow & 15)) << 4) | c8)) = o;
}

// ===========================================================================
// MEGA kernel v5: BM=16, 256 threads, 12 KB LDS -> 8 blocks/CU (thread-cap
// bound, 100% wave cap). 8 independent blocks/CU interleave gather and
// MFMA phases (restores gather issue-rate the fused structure lost), and
// DYNAMIC row stealing (LDS ticket) turns block gather time from max(row
// degrees) into mean (kills the straggler-barrier tax). Per-row ladder and
// per-element MFMA order unchanged -> bit-identical.
// ===========================================================================
#define BM 16

__global__ __launch_bounds__(256, 8) void mega(
    const __bf16* __restrict__ xsb_in,
    const __bf16* __restrict__ xib_in,
    const int* __restrict__ start_r, const int* __restrict__ end_r, const int* __restrict__ eidx_r,
    const int* __restrict__ start_v, const int* __restrict__ end_v, const int* __restrict__ eidx_v,
    const int* __restrict__ start_p, const int* __restrict__ end_p, const int* __restrict__ eidx_p,
    const __bf16* __restrict__ Wl_s, const __bf16* __restrict__ Wr_s, const __bf16* __restrict__ Wp,
    const float*  __restrict__ bl_s, const float*  __restrict__ bp,
    const __bf16* __restrict__ Wl_i, const __bf16* __restrict__ Wr_i,
    const float*  __restrict__ bl_i,
    float* out_s,                       // null at l=0
    __bf16* xsb_out,                    // null at l=1
    float* __restrict__ out_i,          // xi_tmp f32
    float* __restrict__ col_sum, float* __restrict__ col_sum2,
    int nb_item)
{
    __shared__ __align__(16) __bf16 A[3][BM * DD];   // 3 x 4 KB
    __shared__ int ticket;

    int tid  = threadIdx.x;             // 0..255
    int lane = tid & 63;
    int wv   = tid >> 6;                // 0..3
    int sub  = tid & 31;
    int mrow = lane & 15;
    int hi   = lane >> 4;

    if (tid == 0) ticket = 0;

    if (blockIdx.x < nb_item) {
        // ---------------- item path ----------------
        int row0 = blockIdx.x * BM;
        {   // async stage xib rows -> A1: 4 waves x 1 KB = 4 KB
            const char* gx = (const char*)xib_in + (size_t)row0 * 256 + lane * 16;
            int ch = wv * 1024;
            async_copy16((char*)A[1] + ch, gx + ch);
        }
        __syncthreads();                // ticket visible to all half-waves
        // gather agg_r: 16 rows, dynamically stolen by 8 half-waves
        for (;;) {
            int t = 0;
            if (sub == 0) t = atomicAdd(&ticket, 1);
            t = __shfl(t, 0, 32);
            if (t >= BM) break;
            int d = row0 + t;
            int s0 = 0, s1 = 0;
            if (d < NIi) { s0 = start_r[d]; s1 = end_r[d]; }
            gather_row_lds(xsb_in, eidx_r, s0, s1, true, A[0], t, sub);
        }
        asm volatile("s_waitcnt vmcnt(0)" ::: "memory");
        __syncthreads();

        floatx4 acc[2];
        acc[0] = (floatx4){0.f, 0.f, 0.f, 0.f};
        acc[1] = (floatx4){0.f, 0.f, 0.f, 0.f};
        const __bf16* Ws[2] = {Wl_i, Wr_i};
#pragma unroll
        for (int m = 0; m < 2; ++m) {
            bf16x8 bfr[2][4];
#pragma unroll
            for (int ct2 = 0; ct2 < 2; ++ct2) {
                int brow = (wv * 2 + ct2) * 16 + mrow;
#pragma unroll
                for (int kc = 0; kc < 4; ++kc)
                    bfr[ct2][kc] = *(const bf16x8*)(Ws[m] + (size_t)brow * DD + kc * 32 + hi * 8);
            }
            const char* Ar = (const char*)A[m] + mrow * 256;
#pragma unroll
            for (int kc = 0; kc < 4; ++kc) {
                bf16x8 afr = *(const bf16x8*)(Ar + (((kc * 4 + hi) ^ mrow) << 4));
                acc[0] = __builtin_amdgcn_mfma_f32_16x16x32_bf16(afr, bfr[0][kc], acc[0], 0, 0, 0);
                acc[1] = __builtin_amdgcn_mfma_f32_16x16x32_bf16(afr, bfr[1][kc], acc[1], 0, 0, 0);
            }
        }

#pragma unroll
        for (int ct2 = 0; ct2 < 2; ++ct2) {
            int col  = (wv * 2 + ct2) * 16 + mrow;
            float bb = bl_i[col];
            float s = 0.f, s2 = 0.f;
#pragma unroll
            for (int r = 0; r < 4; ++r) {
                int grow = row0 + hi * 4 + r;
                if (grow < NIi) {
                    float vv = acc[ct2][r] + bb;
                    vv = (vv > 0.f) ? vv : expm1f(vv);
                    out_i[(size_t)grow * DD + col] = vv;
                    s += vv; s2 += vv * vv;
                }
            }
            s  += __shfl_xor(s, 16);  s2 += __shfl_xor(s2, 16);
            s  += __shfl_xor(s, 32);  s2 += __shfl_xor(s2, 32);
            if (hi == 0) {
                atomicAdd(col_sum  + col, s);
                atomicAdd(col_sum2 + col, s2);
            }
        }
    } else {
        // ---------------- student path ----------------
        int row0 = (blockIdx.x - nb_item) * BM;
        {   // async stage xsb rows -> A1
            const char* gx = (const char*)xsb_in + (size_t)row0 * 256 + lane * 16;
            int ch = wv * 1024;
            async_copy16((char*)A[1] + ch, gx + ch);
        }
        __syncthreads();                // ticket visible
        // 32 gather tasks (16 rev + 16 prec), dynamically stolen
        for (;;) {
            int t = 0;
            if (sub == 0) t = atomicAdd(&ticket, 1);
            t = __shfl(t, 0, 32);
            if (t >= 2 * BM) break;
            int lrow = t & (BM - 1);
            int d = row0 + lrow;
            bool sim = t >= BM;
            int s0 = 0, s1 = 0;
            if (d < NSs) {
                s0 = sim ? start_p[d] : start_v[d];
                s1 = sim ? end_p[d]   : end_v[d];
            }
            gather_row_lds(sim ? xsb_in : xib_in, sim ? eidx_p : eidx_v,
                           s0, s1, !sim, sim ? A[2] : A[0], lrow, sub);
        }
        asm volatile("s_waitcnt vmcnt(0)" ::: "memory");
        __syncthreads();

        floatx4 acc[2];
        acc[0] = (floatx4){0.f, 0.f, 0.f, 0.f};
        acc[1] = (floatx4){0.f, 0.f, 0.f, 0.f};
        const __bf16* Ws[3] = {Wl_s, Wr_s, Wp};
#pragma unroll
        for (int m = 0; m < 3; ++m) {
            bf16x8 bfr[2][4];
#pragma unroll
            for (int ct2 = 0; ct2 < 2; ++ct2) {
                int brow = (wv * 2 + ct2) * 16 + mrow;
#pragma unroll
                for (int kc = 0; kc < 4; ++kc)
                    bfr[ct2][kc] = *(const bf16x8*)(Ws[m] + (size_t)brow * DD + kc * 32 + hi * 8);
            }
            const char* Ar = (const char*)A[m] + mrow * 256;
#pragma unroll
            for (int kc = 0; kc < 4; ++kc) {
                bf16x8 afr = *(const bf16x8*)(Ar + (((kc * 4 + hi) ^ mrow) << 4));
                acc[0] = __builtin_amdgcn_mfma_f32_16x16x32_bf16(afr, bfr[0][kc], acc[0], 0, 0, 0);
                acc[1] = __builtin_amdgcn_mfma_f32_16x16x32_bf16(afr, bfr[1][kc], acc[1], 0, 0, 0);
            }
        }

        if (out_s) {   // l=1: plain f32 output
#pragma unroll
            for (int ct2 = 0; ct2 < 2; ++ct2) {
                int col  = (wv * 2 + ct2) * 16 + mrow;
                float bb = bl_s[col] + bp[col];
#pragma unroll
                for (int r = 0; r < 4; ++r) {
                    int grow = row0 + hi * 4 + r;
                    if (grow < NSs)
                        out_s[(size_t)grow * DD + col] = 0.5f * (acc[ct2][r] + bb);
                }
            }
        }
        if (xsb_out) { // l=0: bf16 table, LDS-staged -> coalesced 16B stores
            __syncthreads();           // done reading A for MFMA
            __bf16* S = &A[0][0];
#pragma unroll
            for (int ct2 = 0; ct2 < 2; ++ct2) {
                int col  = (wv * 2 + ct2) * 16 + mrow;
                int cch  = col >> 3;
                int cin  = (col & 7) * 2;
                float bb = bl_s[col] + bp[col];
#pragma unroll
                for (int r = 0; r < 4; ++r) {
                    int lrow = hi * 4 + r;
                    float v = 0.5f * (acc[ct2][r] + bb);
                    *(__bf16*)((char*)S + lrow * 256 +
                               (((cch ^ (lrow & 15)) << 4) | cin)) = (__bf16)v;
                }
            }
            __syncthreads();
            char* dst = (char*)xsb_out + (size_t)row0 * 256;
            int o = tid * 16;          // 256 threads x 16 B = 4 KB
            *(bf16x8*)(dst + o) = *(const bf16x8*)((const char*)S + o);
        }
    }
}

// ---------------------------------------------------------------------------
__global__ __launch_bounds__(256) void bn_norm(
    const float* __restrict__ x,
    const float* __restrict__ cs,
    const float* __restrict__ cs2,
    const float* __restrict__ g,
    const float* __restrict__ b,
    float* out,                         // null at l=0
    __bf16* xib_out,                    // null at l=1
    int M)
{
    int i = blockIdx.x * 256 + threadIdx.x;
    if (i >= M * 32) return;
    int row = i >> 5;
    int h   = i & 31;
    int c4  = h << 2;
    float invM = 1.0f / (float)M;
    floatx4 v = *(const floatx4*)(x + (size_t)row * DD + c4);
    floatx4 o;
#pragma unroll
    for (int k = 0; k < 4; ++k) {
        float m = cs[c4 + k] * invM;
        float r = rsqrtf(cs2[c4 + k] * invM - m * m + 1e-5f);
        o[k] = (v[k] - m) * r * g[c4 + k] + b[c4 + k];
    }
    if (out)
        *(floatx4*)(out + (size_t)row * DD + c4) = o;
    if (xib_out) {
        bf16x4 ob = { (__bf16)o.x, (__bf16)o.y, (__bf16)o.z, (__bf16)o.w };
        int phys = (((h >> 1) ^ (row & 15)) << 4) | ((h & 1) << 3);
        *(bf16x4*)((char*)xib_out + (size_t)row * 256 + phys) = ob;
    }
}

// ---------------------------------------------------------------------------
extern "C" void kernel_launch(void* const* d_in, const int* in_sizes, int n_in,
                              void* d_out, int out_size, void* d_ws, size_t ws_size,
                              hipStream_t stream)
{
    const float* x_student = (const float*)d_in[0];
    const float* x_item    = (const float*)d_in[1];
    const float* Wl_ri     = (const float*)d_in[2];
    const float* bl_ri     = (const float*)d_in[3];
    const float* Wr_ri     = (const float*)d_in[4];
    const float* Wl_rs     = (const float*)d_in[5];
    const float* bl_rs     = (const float*)d_in[6];
    const float* Wr_rs     = (const float*)d_in[7];
    const float* W_p       = (const float*)d_in[8];
    const float* b_p       = (const float*)d_in[9];
    const float* bn_g      = (const float*)d_in[10];
    const float* bn_b      = (const float*)d_in[11];
    const int* resp_src = (const int*)d_in[12];
    const int* resp_dst = (const int*)d_in[13];
    const int* rev_src  = (const int*)d_in[14];
    const int* rev_dst  = (const int*)d_in[15];
    const int* prec_src = (const int*)d_in[16];
    const int* prec_dst = (const int*)d_in[17];

    // ---- workspace ----
    char* ws = (char*)d_ws;
    size_t off = 0;
    auto alloc = [&](size_t bytes) -> void* {
        void* p = ws + off;
        off += (bytes + 1023) & ~(size_t)1023;
        return p;
    };
    // zeroed region: CSR counts + fused BN column stats (per layer)
    int* cnt_r  = (int*)alloc(NIi * 4);
    int* cnt_v  = (int*)alloc(NSs * 4);
    int* cnt_p  = (int*)alloc(NSs * 4);
    float* cstat = (float*)alloc(4 * 128 * 4);   // [l0 sum|l0 sum2|l1 sum|l1 sum2]
    size_t zero_bytes = off;
    // CSR arrays + bucket scan state
    int* start_r = (int*)alloc(NIi * 4);
    int* fill_r  = (int*)alloc(NIi * 4);
    int* start_v = (int*)alloc(NSs * 4);
    int* fill_v  = (int*)alloc(NSs * 4);
    int* start_p = (int*)alloc(NSs * 4);
    int* fill_p  = (int*)alloc(NSs * 4);
    int* eidx_r  = (int*)alloc((size_t)E1e * 4);
    int* eidx_v  = (int*)alloc((size_t)E1e * 4);
    int* eidx_p  = (int*)alloc((size_t)E2e * 4);
    int* bsum    = (int*)alloc(NB_ALL * 4);
    int* btick   = (int*)alloc(NB_ALL * 4);
    int* bstart  = (int*)alloc(NB_ALL * 4);
    unsigned int* tmp_r = (unsigned int*)alloc((size_t)E1e * 4);
    unsigned int* tmp_v = (unsigned int*)alloc((size_t)E1e * 4);
    unsigned int* tmp_p = (unsigned int*)alloc((size_t)E2e * 4);
    // bf16 swizzled node tables, double-buffered across layers (+64 rows pad).
    __bf16* xsb0 = (__bf16*)alloc((size_t)(NSs + 64) * DD * 2);
    __bf16* xsb1 = (__bf16*)alloc((size_t)(NSs + 64) * DD * 2);
    __bf16* xib0 = (__bf16*)alloc((size_t)(NIi + 64) * DD * 2);
    __bf16* xib1 = (__bf16*)alloc((size_t)(NIi + 64) * DD * 2);
    __bf16* wbf  = (__bf16*)alloc((size_t)5 * 32768 * 2);
    float* xi_tmp = (float*)alloc((size_t)NIi * DD * 4);
    (void)ws_size; (void)in_sizes; (void)n_in; (void)out_size;

    float* out_xi = (float*)d_out;                    // xi_2
    float* out_xs = out_xi + (size_t)NIi * DD;        // xs_2

    const long Etot = 2L * E1e + E2e;
    const int eblocks = (int)((Etot + 255) / 256);
    const int nbr_blocks = (E1e + TILE - 1) / TILE;         // 74
    const int nbv_blocks = (E1e + TILE - 1) / TILE;         // 74
    const int nbp_blocks = (E2e + TILE - 1) / TILE;         // 62
    const int gi_blocks  = (NIi + BM - 1) / BM;             // 1250 (item)
    const int gs_blocks  = (NSs + BM - 1) / BM;             // 6250 (stu)
    const int bnn_blocks = (NIi * 32 + 255) / 256;
    const int wblocks    = 640;
    const int sblocks    = (NSs * 16 + 255) / 256;
    const int iblocks    = (NIi * 16 + 255) / 256;

    __bf16* wb_l_ri = wbf + 0 * 32768;
    __bf16* wb_r_ri = wbf + 1 * 32768;
    __bf16* wb_l_rs = wbf + 2 * 32768;
    __bf16* wb_r_rs = wbf + 3 * 32768;
    __bf16* wb_p    = wbf + 4 * 32768;

    hipMemsetAsync(ws, 0, zero_bytes, stream);
    prep1<<<wblocks + sblocks + iblocks + eblocks, 256, 0, stream>>>(
        Wl_ri, Wr_ri, Wl_rs, Wr_rs, W_p, wbf,
        x_student, xsb0, x_item, xib0,
        resp_dst, rev_dst, prec_dst,
        cnt_r, cnt_v, cnt_p,
        wblocks, sblocks, iblocks);
    scanA<<<NB_ALL, 256, 0, stream>>>(cnt_r, cnt_v, cnt_p,
                                      start_r, start_v, start_p, bsum);
    scanB<<<1, 1024, 0, stream>>>(bsum, btick, bstart);
    scanCbinB<<<NB_ALL + nbr_blocks + nbv_blocks + nbp_blocks, 256, 0, stream>>>(
        start_r, fill_r, start_v, fill_v, start_p, fill_p,
        bstart, btick,
        resp_src, resp_dst, rev_src, rev_dst, prec_src, prec_dst,
        tmp_r, tmp_v, tmp_p,
        nbr_blocks, nbv_blocks);
    binC<<<NB_ALL, 256, 0, stream>>>(bstart, btick, tmp_r, tmp_v, tmp_p,
                                     fill_r, fill_v, fill_p,
                                     eidx_r, eidx_v, eidx_p);
    // after binC, fill_x[d] == end of segment d

    for (int l = 0; l < 2; l++) {
        size_t wOfs = (size_t)l * DD * DD;
        size_t bOfs = (size_t)l * DD;
        float* cs  = cstat + (size_t)l * 256;
        float* cs2 = cs + 128;
        const __bf16* xsb_in = (l == 0) ? xsb0 : xsb1;
        const __bf16* xib_in = (l == 0) ? xib0 : xib1;
        __bf16* xsb_next = (l == 0) ? xsb1 : nullptr;
        __bf16* xib_next = (l == 0) ? xib1 : nullptr;
        float* f32_xs    = (l == 0) ? nullptr : out_xs;
        float* f32_xi    = (l == 0) ? nullptr : out_xi;

        mega<<<gi_blocks + gs_blocks, 256, 0, stream>>>(
            xsb_in, xib_in,
            start_r, fill_r, eidx_r,
            start_v, fill_v, eidx_v,
            start_p, fill_p, eidx_p,
            wb_l_rs + wOfs, wb_r_rs + wOfs, wb_p + wOfs,
            bl_rs + bOfs, b_p + bOfs,
            wb_l_ri + wOfs, wb_r_ri + wOfs, bl_ri + bOfs,
            f32_xs, xsb_next,
            xi_tmp, cs, cs2,
            gi_blocks);

        bn_norm<<<bnn_blocks, 256, 0, stream>>>(xi_tmp, cs, cs2,
                                                bn_g + bOfs, bn_b + bOfs,
                                                f32_xi, xib_next, NIi);
    }
}

// Round 13
// 457.421 us; speedup vs baseline: 1.3291x; 1.3291x over previous
//
#include <hip/hip_runtime.h>

#define NSs 100000
#define NIi 20000
#define DD  128
#define E1e 600000
#define E2e 500000

// bucket/scan geometry: 256 dsts per bucket
#define NB_R 79                      // ceil(20000/256)
#define NB_V 391                     // ceil(100000/256)
#define NB_P 391
#define NB_ALL (NB_R + NB_V + NB_P)  // 861; seg bounds 79 / 470
#define TILE 8192                    // edges per binB/histB block

typedef __attribute__((ext_vector_type(8))) __bf16 bf16x8;
typedef __attribute__((ext_vector_type(4))) __bf16 bf16x4;
typedef __attribute__((ext_vector_type(4))) float  floatx4;

__device__ __forceinline__ void async_copy16(void* lds, const void* gsrc)
{
    __builtin_amdgcn_global_load_lds(
        (const __attribute__((address_space(1))) void*)gsrc,
        (__attribute__((address_space(3))) void*)lds, 16, 0, 0);
}

__device__ __forceinline__ floatx4 cvt4(bf16x4 v)
{
    return (floatx4){ (float)v.x, (float)v.y, (float)v.z, (float)v.w };
}

// Swizzled-row addressing: 16B chunk c of row r lives at chunk c ^ (r&15).
__device__ __forceinline__ const char* swz_addr(
    const __bf16* tab, int r, int c16, int c8)
{
    return (const char*)tab + (size_t)r * 256 + (((c16 ^ (r & 15)) << 4) | c8);
}

// ===========================================================================
// prep1: fused conversions (weights + node tables) AND the bucket-level
// histogram (LDS hist per tile -> ~82K global atomics vs 1.7M per-dst).
// ===========================================================================
__global__ __launch_bounds__(256) void prep1(
    const float* __restrict__ Wa, const float* __restrict__ Wb,
    const float* __restrict__ Wc, const float* __restrict__ Wd,
    const float* __restrict__ We, __bf16* __restrict__ wbf,
    const float* __restrict__ xs_in, __bf16* __restrict__ xsb,
    const float* __restrict__ xi_in, __bf16* __restrict__ xib,
    const int* __restrict__ rd, const int* __restrict__ vd,
    const int* __restrict__ pd,
    int* __restrict__ bsum,
    int wblocks, int sblocks, int iblocks,
    int nbr_blocks, int nbv_blocks)
{
    __shared__ int lhist[NB_V];
    int b = blockIdx.x;
    int cvtb = wblocks + sblocks + iblocks;
    if (b < cvtb) {
        if (b < wblocks) {
            int i = b * 256 + threadIdx.x;
            const float* srcs[5] = {Wa, Wb, Wc, Wd, We};
            wbf[i] = (__bf16)srcs[i >> 15][i & 32767];
            return;
        }
        const float* in; __bf16* out; int i; int M;
        if (b < wblocks + sblocks) {
            in = xs_in; out = xsb; M = NSs;
            i = (b - wblocks) * 256 + threadIdx.x;
        } else {
            in = xi_in; out = xib; M = NIi;
            i = (b - wblocks - sblocks) * 256 + threadIdx.x;
        }
        if (i >= M * 16) return;
        int r = i >> 4, c = i & 15;
        const float* p = in + (size_t)r * DD + c * 8;
        floatx4 a = *(const floatx4*)p;
        floatx4 d = *(const floatx4*)(p + 4);
        bf16x8 o = { (__bf16)a.x, (__bf16)a.y, (__bf16)a.z, (__bf16)a.w,
                     (__bf16)d.x, (__bf16)d.y, (__bf16)d.z, (__bf16)d.w };
        *(bf16x8*)((char*)out + (size_t)r * 256 + ((c ^ (r & 15)) << 4)) = o;
        return;
    }
    // ---- bucket-level histogram (one relation tile per block) ----
    int bb2 = b - cvtb;
    const int* dst; long e0; long ecnt; int tickofs; int nbkt;
    if (bb2 < nbr_blocks) {
        dst = rd; e0 = (long)bb2 * TILE; ecnt = E1e; tickofs = 0; nbkt = NB_R;
    } else if (bb2 < nbr_blocks + nbv_blocks) {
        dst = vd; e0 = (long)(bb2 - nbr_blocks) * TILE; ecnt = E1e;
        tickofs = NB_R; nbkt = NB_V;
    } else {
        dst = pd; e0 = (long)(bb2 - nbr_blocks - nbv_blocks) * TILE;
        ecnt = E2e; tickofs = NB_R + NB_V; nbkt = NB_P;
    }
    int tid = threadIdx.x;
    for (int i = tid; i < nbkt; i += 256) lhist[i] = 0;
    __syncthreads();
    long e1 = e0 + TILE; if (e1 > ecnt) e1 = ecnt;
    for (long e = e0 + tid; e < e1; e += 256)
        atomicAdd(&lhist[dst[e] >> 8], 1);
    __syncthreads();
    for (int i = tid; i < nbkt; i += 256) {
        int c = lhist[i];
        if (c) atomicAdd(bsum + tickofs + i, c);
    }
}

// scanB: one block, segmented exclusive scan of bsum[861] -> btick & bstart.
__global__ __launch_bounds__(1024) void scanB(
    const int* __restrict__ bsum,
    int* __restrict__ btick, int* __restrict__ bstart)
{
    int tid = threadIdx.x;
    int v = (tid < NB_ALL) ? bsum[tid] : 0;
    int lane = tid & 63, w = tid >> 6;       // 16 waves
    int s = v;
#pragma unroll
    for (int o = 1; o < 64; o <<= 1) {
        int u = __shfl_up(s, o, 64);
        if (lane >= o) s += u;
    }
    __shared__ int ws[16];
    if (lane == 63) ws[w] = s;
    __syncthreads();
    int wofs = 0;
    for (int k = 0; k < 16; ++k) if (k < w) wofs += ws[k];
    int excl = wofs + s - v;                 // global exclusive scan
    __shared__ int segbase[3];
    if (tid == 0)      segbase[0] = 0;
    if (tid == NB_R)   segbase[1] = excl;
    if (tid == NB_R + NB_V) segbase[2] = excl;
    __syncthreads();
    if (tid < NB_ALL) {
        int sb = (tid < NB_R) ? segbase[0]
               : (tid < NB_R + NB_V) ? segbase[1] : segbase[2];
        int val = excl - sb;                 // relation-local bucket start
        btick[tid]  = val;
        bstart[tid] = val;
    }
}

// ===========================================================================
// binB: LDS-histogram radix binning into bucket-sorted tmp (block-level
// bucket reservation; ~82K global atomics). pack: u32 = src | (dst&255)<<17.
// ===========================================================================
__global__ __launch_bounds__(256) void binB(
    int* __restrict__ btick,
    const int* __restrict__ rs, const int* __restrict__ rd,
    const int* __restrict__ vs, const int* __restrict__ vd,
    const int* __restrict__ ps, const int* __restrict__ pd,
    unsigned int* __restrict__ tr, unsigned int* __restrict__ tv,
    unsigned int* __restrict__ tp,
    int nbr_blocks, int nbv_blocks)
{
    __shared__ int lhist[NB_V];
    __shared__ int lbase[NB_V];
    int b = blockIdx.x;
    const int* src; const int* dst; unsigned int* tmp;
    long e0; long ecnt; int tickofs; int nbkt;
    if (b < nbr_blocks) {
        src = rs; dst = rd; tmp = tr; e0 = (long)b * TILE; ecnt = E1e;
        tickofs = 0; nbkt = NB_R;
    } else if (b < nbr_blocks + nbv_blocks) {
        src = vs; dst = vd; tmp = tv; e0 = (long)(b - nbr_blocks) * TILE;
        ecnt = E1e; tickofs = NB_R; nbkt = NB_V;
    } else {
        src = ps; dst = pd; tmp = tp;
        e0 = (long)(b - nbr_blocks - nbv_blocks) * TILE; ecnt = E2e;
        tickofs = NB_R + NB_V; nbkt = NB_P;
    }
    int tid = threadIdx.x;
    for (int i = tid; i < nbkt; i += 256) lhist[i] = 0;
    __syncthreads();
    long e1 = e0 + TILE; if (e1 > ecnt) e1 = ecnt;
    for (long e = e0 + tid; e < e1; e += 256)
        atomicAdd(&lhist[dst[e] >> 8], 1);
    __syncthreads();
    for (int i = tid; i < nbkt; i += 256) {
        int c = lhist[i];
        lbase[i] = c ? atomicAdd(btick + tickofs + i, c) : 0;
        lhist[i] = 0;                        // reuse as running offset
    }
    __syncthreads();
    for (long e = e0 + tid; e < e1; e += 256) {
        int d = dst[e];
        int bk = d >> 8;
        int pos = lbase[bk] + atomicAdd(&lhist[bk], 1);
        tmp[pos] = (unsigned int)src[e] | ((unsigned int)(d & 255) << 17);
    }
}

// ===========================================================================
// binC v2: one block per bucket. Recomputes per-dst counts in LDS, block-
// scans them, writes start[]/end[] as COALESCED stores (replaces scanA +
// 1.7M global fill atomics), then places edges via LDS running offsets.
// ===========================================================================
__global__ __launch_bounds__(256) void binC(
    const int* __restrict__ bstart, const int* __restrict__ btick,
    const unsigned int* __restrict__ tr, const unsigned int* __restrict__ tv,
    const unsigned int* __restrict__ tp,
    int* __restrict__ sr, int* __restrict__ er2,
    int* __restrict__ sv, int* __restrict__ ev2,
    int* __restrict__ sp, int* __restrict__ ep2,
    int* __restrict__ er, int* __restrict__ ev, int* __restrict__ ep)
{
    __shared__ int lcnt[256];
    __shared__ int lrun[256];
    __shared__ int wsum[4];
    int b = blockIdx.x;
    const unsigned int* tmp; int* startA; int* endA; int* eidx;
    int dstbase; int n;
    if (b < NB_R) {
        tmp = tr; startA = sr; endA = er2; eidx = er; dstbase = b << 8; n = NIi;
    } else if (b < NB_R + NB_V) {
        tmp = tv; startA = sv; endA = ev2; eidx = ev;
        dstbase = (b - NB_R) << 8; n = NSs;
    } else {
        tmp = tp; startA = sp; endA = ep2; eidx = ep;
        dstbase = (b - NB_R - NB_V) << 8; n = NSs;
    }
    int tid = threadIdx.x;
    lcnt[tid] = 0;
    __syncthreads();
    int bs = bstart[b], be = btick[b];       // btick == bucket end after binB
    for (int e = bs + tid; e < be; e += 256)
        atomicAdd(&lcnt[tmp[e] >> 17], 1);
    __syncthreads();
    // block exclusive scan of lcnt[256]
    int c = lcnt[tid];
    int lane = tid & 63, w = tid >> 6;
    int sum = c;
#pragma unroll
    for (int o = 1; o < 64; o <<= 1) {
        int u = __shfl_up(sum, o, 64);
        if (lane >= o) sum += u;
    }
    if (lane == 63) wsum[w] = sum;
    __syncthreads();
    int wofs = 0;
    for (int k = 0; k < 4; ++k) if (k < w) wofs += wsum[k];
    int excl = wofs + sum - c;
    int d = dstbase + tid;
    if (d < n) {
        startA[d] = bs + excl;
        endA[d]   = bs + excl + c;
    }
    lrun[tid] = bs + excl;
    __syncthreads();
    for (int e = bs + tid; e < be; e += 256) {
        unsigned int v = tmp[e];
        int li = (int)(v >> 17);
        int pos = atomicAdd(&lrun[li], 1);   // LDS atomic, not global
        eidx[pos] = (int)(v & 0x1FFFFu);
    }
}

// ===========================================================================
// Per-row gather into LDS (16/8/4/2/1 ladder; bit-identical per-row order).
// ===========================================================================
__device__ __forceinline__ void gather_row_lds(
    const __bf16* __restrict__ x,
    const int* __restrict__ eidx,
    int s0, int s1, bool mean,
    __bf16* __restrict__ Abase, int lrow, int sub)
{
    int c16 = sub >> 1;
    int c8  = (sub & 1) << 3;
    floatx4 acc = {0.f, 0.f, 0.f, 0.f};
    int base = s0;
    while (base < s1) {
        int chunk = s1 - base; if (chunk > 32) chunk = 32;
        int my_e = eidx[base + (sub < chunk ? sub : chunk - 1)];
        int j = 0;
        for (; j + 16 <= chunk; j += 16) {
            bf16x4 v[16];
#pragma unroll
            for (int k = 0; k < 16; ++k) {
                int rr = __shfl(my_e, j + k, 32);
                v[k] = *(const bf16x4*)swz_addr(x, rr, c16, c8);
            }
            floatx4 t0 = (cvt4(v[0]) + cvt4(v[1])) + (cvt4(v[2]) + cvt4(v[3]));
            floatx4 t1 = (cvt4(v[4]) + cvt4(v[5])) + (cvt4(v[6]) + cvt4(v[7]));
            floatx4 t2 = (cvt4(v[8]) + cvt4(v[9])) + (cvt4(v[10]) + cvt4(v[11]));
            floatx4 t3 = (cvt4(v[12]) + cvt4(v[13])) + (cvt4(v[14]) + cvt4(v[15]));
            acc += (t0 + t1) + (t2 + t3);
        }
        if (j + 8 <= chunk) {
            bf16x4 v[8];
#pragma unroll
            for (int k = 0; k < 8; ++k) {
                int rr = __shfl(my_e, j + k, 32);
                v[k] = *(const bf16x4*)swz_addr(x, rr, c16, c8);
            }
            acc += ((cvt4(v[0]) + cvt4(v[1])) + (cvt4(v[2]) + cvt4(v[3]))) +
                   ((cvt4(v[4]) + cvt4(v[5])) + (cvt4(v[6]) + cvt4(v[7])));
            j += 8;
        }
        if (j + 4 <= chunk) {
            bf16x4 v[4];
#pragma unroll
            for (int k = 0; k < 4; ++k) {
                int rr = __shfl(my_e, j + k, 32);
                v[k] = *(const bf16x4*)swz_addr(x, rr, c16, c8);
            }
            acc += (cvt4(v[0]) + cvt4(v[1])) + (cvt4(v[2]) + cvt4(v[3]));
            j += 4;
        }
        if (j + 2 <= chunk) {
            int r0 = __shfl(my_e, j + 0, 32);
            int r1 = __shfl(my_e, j + 1, 32);
            bf16x4 v0 = *(const bf16x4*)swz_addr(x, r0, c16, c8);
            bf16x4 v1 = *(const bf16x4*)swz_addr(x, r1, c16, c8);
            acc += cvt4(v0) + cvt4(v1);
            j += 2;
        }
        if (j < chunk) {
            int r0 = __shfl(my_e, j, 32);
            acc += cvt4(*(const bf16x4*)swz_addr(x, r0, c16, c8));
        }
        base += chunk;
    }
    if (mean) {
        int deg = s1 - s0;
        float inv = 1.0f / (float)(deg > 1 ? deg : 1);
        acc.x *= inv; acc.y *= inv; acc.z *= inv; acc.w *= inv;
    }
    bf16x4 o = { (__bf16)acc.x, (__bf16)acc.y, (__bf16)acc.z, (__bf16)acc.w };
    *(bf16x4*)((char*)Abase + lrow * 256 + (((c16 ^ (lrow & 15)) << 4) | c8)) = o;
}

// ===========================================================================
// MEGA kernel: R7 config restored (best measured: 120 us/layer).
// BM=32, 256 threads, 24 KB LDS, static task assignment.
// ===========================================================================
#define BM 32

__global__ __launch_bounds__(256, 6) void mega(
    const __bf16* __restrict__ xsb_in,
    const __bf16* __restrict__ xib_in,
    const int* __restrict__ start_r, const int* __restrict__ end_r, const int* __restrict__ eidx_r,
    const int* __restrict__ start_v, const int* __restrict__ end_v, const int* __restrict__ eidx_v,
    const int* __restrict__ start_p, const int* __restrict__ end_p, const int* __restrict__ eidx_p,
    const __bf16* __restrict__ Wl_s, const __bf16* __restrict__ Wr_s, const __bf16* __restrict__ Wp,
    const float*  __restrict__ bl_s, const float*  __restrict__ bp,
    const __bf16* __restrict__ Wl_i, const __bf16* __restrict__ Wr_i,
    const float*  __restrict__ bl_i,
    float* out_s,                       // null at l=0
    __bf16* xsb_out,                    // null at l=1
    float* __restrict__ out_i,          // xi_tmp f32
    float* __restrict__ col_sum, float* __restrict__ col_sum2,
    int nb_item)
{
    __shared__ __align__(16) __bf16 A[3][BM * DD];   // 3 x 8 KB

    int tid  = threadIdx.x;
    int lane = tid & 63;
    int wv   = tid >> 6;
    int hw   = tid >> 5;                // half-wave id 0..7
    int sub  = tid & 31;
    int mrow = lane & 15;
    int hi   = lane >> 4;

    if (blockIdx.x < nb_item) {
        // ---------------- item path ----------------
        int row0 = blockIdx.x * BM;
        {
            const char* gx = (const char*)xib_in + (size_t)row0 * 256 + lane * 16;
#pragma unroll
            for (int j = 0; j < 2; ++j) {
                int ch = (wv * 2 + j) * 1024;
                async_copy16((char*)A[1] + ch, gx + ch);
            }
        }
        for (int t = 0; t < 4; ++t) {
            int lrow = hw + t * 8;
            int d = row0 + lrow;
            int s0 = 0, s1 = 0;
            if (d < NIi) { s0 = start_r[d]; s1 = end_r[d]; }
            gather_row_lds(xsb_in, eidx_r, s0, s1, true, A[0], lrow, sub);
        }
        asm volatile("s_waitcnt vmcnt(0)" ::: "memory");
        __syncthreads();

        floatx4 acc[2][2];
#pragma unroll
        for (int a = 0; a < 2; ++a) {
            acc[a][0] = (floatx4){0.f, 0.f, 0.f, 0.f};
            acc[a][1] = (floatx4){0.f, 0.f, 0.f, 0.f};
        }
        const __bf16* Ws[2] = {Wl_i, Wr_i};
#pragma unroll
        for (int m = 0; m < 2; ++m) {
            bf16x8 bfr[2][4];
#pragma unroll
            for (int ct2 = 0; ct2 < 2; ++ct2) {
                int brow = (wv * 2 + ct2) * 16 + mrow;
#pragma unroll
                for (int kc = 0; kc < 4; ++kc)
                    bfr[ct2][kc] = *(const bf16x8*)(Ws[m] + (size_t)brow * DD + kc * 32 + hi * 8);
            }
            const char* Ab = (const char*)A[m];
#pragma unroll
            for (int rt = 0; rt < 2; ++rt) {
                const char* Ar = Ab + (rt * 16 + mrow) * 256;
#pragma unroll
                for (int kc = 0; kc < 4; ++kc) {
                    bf16x8 afr = *(const bf16x8*)(Ar + (((kc * 4 + hi) ^ mrow) << 4));
                    acc[rt][0] = __builtin_amdgcn_mfma_f32_16x16x32_bf16(afr, bfr[0][kc], acc[rt][0], 0, 0, 0);
                    acc[rt][1] = __builtin_amdgcn_mfma_f32_16x16x32_bf16(afr, bfr[1][kc], acc[rt][1], 0, 0, 0);
                }
            }
        }

#pragma unroll
        for (int ct2 = 0; ct2 < 2; ++ct2) {
            int col  = (wv * 2 + ct2) * 16 + mrow;
            float bb = bl_i[col];
            float s = 0.f, s2 = 0.f;
#pragma unroll
            for (int rt = 0; rt < 2; ++rt) {
#pragma unroll
                for (int r = 0; r < 4; ++r) {
                    int grow = row0 + rt * 16 + hi * 4 + r;
                    if (grow < NIi) {
                        float vv = acc[rt][ct2][r] + bb;
                        vv = (vv > 0.f) ? vv : expm1f(vv);
                        out_i[(size_t)grow * DD + col] = vv;
                        s += vv; s2 += vv * vv;
                    }
                }
            }
            s  += __shfl_xor(s, 16);  s2 += __shfl_xor(s2, 16);
            s  += __shfl_xor(s, 32);  s2 += __shfl_xor(s2, 32);
            if (hi == 0) {
                atomicAdd(col_sum  + col, s);
                atomicAdd(col_sum2 + col, s2);
            }
        }
    } else {
        // ---------------- student path ----------------
        int row0 = (blockIdx.x - nb_item) * BM;
        {
            const char* gx = (const char*)xsb_in + (size_t)row0 * 256 + lane * 16;
#pragma unroll
            for (int j = 0; j < 2; ++j) {
                int ch = (wv * 2 + j) * 1024;
                async_copy16((char*)A[1] + ch, gx + ch);
            }
        }
        for (int t = 0; t < 8; ++t) {
            int task = hw + t * 8;
            int lrow = task & 31;
            int d = row0 + lrow;
            bool sim = task >= 32;
            int s0 = 0, s1 = 0;
            if (d < NSs) {
                s0 = sim ? start_p[d] : start_v[d];
                s1 = sim ? end_p[d]   : end_v[d];
            }
            gather_row_lds(sim ? xsb_in : xib_in, sim ? eidx_p : eidx_v,
                           s0, s1, !sim, sim ? A[2] : A[0], lrow, sub);
        }
        asm volatile("s_waitcnt vmcnt(0)" ::: "memory");
        __syncthreads();

        floatx4 acc[2][2];
#pragma unroll
        for (int a = 0; a < 2; ++a) {
            acc[a][0] = (floatx4){0.f, 0.f, 0.f, 0.f};
            acc[a][1] = (floatx4){0.f, 0.f, 0.f, 0.f};
        }
        const __bf16* Ws[3] = {Wl_s, Wr_s, Wp};
#pragma unroll
        for (int m = 0; m < 3; ++m) {
            bf16x8 bfr[2][4];
#pragma unroll
            for (int ct2 = 0; ct2 < 2; ++ct2) {
                int brow = (wv * 2 + ct2) * 16 + mrow;
#pragma unroll
                for (int kc = 0; kc < 4; ++kc)
                    bfr[ct2][kc] = *(const bf16x8*)(Ws[m] + (size_t)brow * DD + kc * 32 + hi * 8);
            }
            const char* Ab = (const char*)A[m];
#pragma unroll
            for (int rt = 0; rt < 2; ++rt) {
                const char* Ar = Ab + (rt * 16 + mrow) * 256;
#pragma unroll
                for (int kc = 0; kc < 4; ++kc) {
                    bf16x8 afr = *(const bf16x8*)(Ar + (((kc * 4 + hi) ^ mrow) << 4));
                    acc[rt][0] = __builtin_amdgcn_mfma_f32_16x16x32_bf16(afr, bfr[0][kc], acc[rt][0], 0, 0, 0);
                    acc[rt][1] = __builtin_amdgcn_mfma_f32_16x16x32_bf16(afr, bfr[1][kc], acc[rt][1], 0, 0, 0);
                }
            }
        }

        if (out_s) {   // l=1: plain f32 output
#pragma unroll
            for (int ct2 = 0; ct2 < 2; ++ct2) {
                int col  = (wv * 2 + ct2) * 16 + mrow;
                float bb = bl_s[col] + bp[col];
#pragma unroll
                for (int rt = 0; rt < 2; ++rt) {
#pragma unroll
                    for (int r = 0; r < 4; ++r) {
                        int grow = row0 + rt * 16 + hi * 4 + r;
                        if (grow < NSs)
                            out_s[(size_t)grow * DD + col] = 0.5f * (acc[rt][ct2][r] + bb);
                    }
                }
            }
        }
        if (xsb_out) { // l=0: bf16 table, LDS-staged -> coalesced 16B stores
            __syncthreads();
            __bf16* S = &A[0][0];
#pragma unroll
            for (int ct2 = 0; ct2 < 2; ++ct2) {
                int col  = (wv * 2 + ct2) * 16 + mrow;
                int cch  = col >> 3;
                int cin  = (col & 7) * 2;
                float bb = bl_s[col] + bp[col];
#pragma unroll
                for (int rt = 0; rt < 2; ++rt) {
#pragma unroll
                    for (int r = 0; r < 4; ++r) {
                        int lrow = rt * 16 + hi * 4 + r;
                        float v = 0.5f * (acc[rt][ct2][r] + bb);
                        *(__bf16*)((char*)S + lrow * 256 +
                                   (((cch ^ (lrow & 15)) << 4) | cin)) = (__bf16)v;
                    }
                }
            }
            __syncthreads();
            char* dst = (char*)xsb_out + (size_t)row0 * 256;
#pragma unroll
            for (int k = 0; k < 2; ++k) {
                int o = tid * 16 + k * 4096;
                *(bf16x8*)(dst + o) = *(const bf16x8*)((const char*)S + o);
            }
        }
    }
}

// ---------------------------------------------------------------------------
__global__ __launch_bounds__(256) void bn_norm(
    const float* __restrict__ x,
    const float* __restrict__ cs,
    const float* __restrict__ cs2,
    const float* __restrict__ g,
    const float* __restrict__ b,
    float* out,                         // null at l=0
    __bf16* xib_out,                    // null at l=1
    int M)
{
    int i = blockIdx.x * 256 + threadIdx.x;
    if (i >= M * 32) return;
    int row = i >> 5;
    int h   = i & 31;
    int c4  = h << 2;
    float invM = 1.0f / (float)M;
    floatx4 v = *(const floatx4*)(x + (size_t)row * DD + c4);
    floatx4 o;
#pragma unroll
    for (int k = 0; k < 4; ++k) {
        float m = cs[c4 + k] * invM;
        float r = rsqrtf(cs2[c4 + k] * invM - m * m + 1e-5f);
        o[k] = (v[k] - m) * r * g[c4 + k] + b[c4 + k];
    }
    if (out)
        *(floatx4*)(out + (size_t)row * DD + c4) = o;
    if (xib_out) {
        bf16x4 ob = { (__bf16)o.x, (__bf16)o.y, (__bf16)o.z, (__bf16)o.w };
        int phys = (((h >> 1) ^ (row & 15)) << 4) | ((h & 1) << 3);
        *(bf16x4*)((char*)xib_out + (size_t)row * 256 + phys) = ob;
    }
}

// ---------------------------------------------------------------------------
extern "C" void kernel_launch(void* const* d_in, const int* in_sizes, int n_in,
                              void* d_out, int out_size, void* d_ws, size_t ws_size,
                              hipStream_t stream)
{
    const float* x_student = (const float*)d_in[0];
    const float* x_item    = (const float*)d_in[1];
    const float* Wl_ri     = (const float*)d_in[2];
    const float* bl_ri     = (const float*)d_in[3];
    const float* Wr_ri     = (const float*)d_in[4];
    const float* Wl_rs     = (const float*)d_in[5];
    const float* bl_rs     = (const float*)d_in[6];
    const float* Wr_rs     = (const float*)d_in[7];
    const float* W_p       = (const float*)d_in[8];
    const float* b_p       = (const float*)d_in[9];
    const float* bn_g      = (const float*)d_in[10];
    const float* bn_b      = (const float*)d_in[11];
    const int* resp_src = (const int*)d_in[12];
    const int* resp_dst = (const int*)d_in[13];
    const int* rev_src  = (const int*)d_in[14];
    const int* rev_dst  = (const int*)d_in[15];
    const int* prec_src = (const int*)d_in[16];
    const int* prec_dst = (const int*)d_in[17];

    // ---- workspace ----
    char* ws = (char*)d_ws;
    size_t off = 0;
    auto alloc = [&](size_t bytes) -> void* {
        void* p = ws + off;
        off += (bytes + 1023) & ~(size_t)1023;
        return p;
    };
    // zeroed region: bucket sums + fused BN column stats (per layer) — tiny
    int* bsum    = (int*)alloc(NB_ALL * 4);
    float* cstat = (float*)alloc(4 * 128 * 4);   // [l0 sum|l0 sum2|l1 sum|l1 sum2]
    size_t zero_bytes = off;                     // ~6 KB
    // CSR arrays + bucket scan state
    int* start_r = (int*)alloc(NIi * 4);
    int* end_r   = (int*)alloc(NIi * 4);
    int* start_v = (int*)alloc(NSs * 4);
    int* end_v   = (int*)alloc(NSs * 4);
    int* start_p = (int*)alloc(NSs * 4);
    int* end_p   = (int*)alloc(NSs * 4);
    int* eidx_r  = (int*)alloc((size_t)E1e * 4);
    int* eidx_v  = (int*)alloc((size_t)E1e * 4);
    int* eidx_p  = (int*)alloc((size_t)E2e * 4);
    int* btick   = (int*)alloc(NB_ALL * 4);
    int* bstart  = (int*)alloc(NB_ALL * 4);
    unsigned int* tmp_r = (unsigned int*)alloc((size_t)E1e * 4);
    unsigned int* tmp_v = (unsigned int*)alloc((size_t)E1e * 4);
    unsigned int* tmp_p = (unsigned int*)alloc((size_t)E2e * 4);
    // bf16 swizzled node tables, double-buffered across layers (+64 rows pad).
    __bf16* xsb0 = (__bf16*)alloc((size_t)(NSs + 64) * DD * 2);
    __bf16* xsb1 = (__bf16*)alloc((size_t)(NSs + 64) * DD * 2);
    __bf16* xib0 = (__bf16*)alloc((size_t)(NIi + 64) * DD * 2);
    __bf16* xib1 = (__bf16*)alloc((size_t)(NIi + 64) * DD * 2);
    __bf16* wbf  = (__bf16*)alloc((size_t)5 * 32768 * 2);
    float* xi_tmp = (float*)alloc((size_t)NIi * DD * 4);
    (void)ws_size; (void)in_sizes; (void)n_in; (void)out_size;

    float* out_xi = (float*)d_out;                    // xi_2
    float* out_xs = out_xi + (size_t)NIi * DD;        // xs_2

    const int nbr_blocks = (E1e + TILE - 1) / TILE;         // 74
    const int nbv_blocks = (E1e + TILE - 1) / TILE;         // 74
    const int nbp_blocks = (E2e + TILE - 1) / TILE;         // 62
    const int hblocks    = nbr_blocks + nbv_blocks + nbp_blocks;
    const int gi_blocks  = (NIi + BM - 1) / BM;             // 625 (item)
    const int gs_blocks  = (NSs + BM - 1) / BM;             // 3125 (stu)
    const int bnn_blocks = (NIi * 32 + 255) / 256;
    const int wblocks    = 640;
    const int sblocks    = (NSs * 16 + 255) / 256;
    const int iblocks    = (NIi * 16 + 255) / 256;

    __bf16* wb_l_ri = wbf + 0 * 32768;
    __bf16* wb_r_ri = wbf + 1 * 32768;
    __bf16* wb_l_rs = wbf + 2 * 32768;
    __bf16* wb_r_rs = wbf + 3 * 32768;
    __bf16* wb_p    = wbf + 4 * 32768;

    hipMemsetAsync(ws, 0, zero_bytes, stream);
    prep1<<<wblocks + sblocks + iblocks + hblocks, 256, 0, stream>>>(
        Wl_ri, Wr_ri, Wl_rs, Wr_rs, W_p, wbf,
        x_student, xsb0, x_item, xib0,
        resp_dst, rev_dst, prec_dst,
        bsum,
        wblocks, sblocks, iblocks, nbr_blocks, nbv_blocks);
    scanB<<<1, 1024, 0, stream>>>(bsum, btick, bstart);
    binB<<<hblocks, 256, 0, stream>>>(
        btick,
        resp_src, resp_dst, rev_src, rev_dst, prec_src, prec_dst,
        tmp_r, tmp_v, tmp_p,
        nbr_blocks, nbv_blocks);
    binC<<<NB_ALL, 256, 0, stream>>>(bstart, btick, tmp_r, tmp_v, tmp_p,
                                     start_r, end_r, start_v, end_v,
                                     start_p, end_p,
                                     eidx_r, eidx_v, eidx_p);

    for (int l = 0; l < 2; l++) {
        size_t wOfs = (size_t)l * DD * DD;
        size_t bOfs = (size_t)l * DD;
        float* cs  = cstat + (size_t)l * 256;
        float* cs2 = cs + 128;
        const __bf16* xsb_in = (l == 0) ? xsb0 : xsb1;
        const __bf16* xib_in = (l == 0) ? xib0 : xib1;
        __bf16* xsb_next = (l == 0) ? xsb1 : nullptr;
        __bf16* xib_next = (l == 0) ? xib1 : nullptr;
        float* f32_xs    = (l == 0) ? nullptr : out_xs;
        float* f32_xi    = (l == 0) ? nullptr : out_xi;

        mega<<<gi_blocks + gs_blocks, 256, 0, stream>>>(
            xsb_in, xib_in,
            start_r, end_r, eidx_r,
            start_v, end_v, eidx_v,
            start_p, end_p, eidx_p,
            wb_l_rs + wOfs, wb_r_rs + wOfs, wb_p + wOfs,
            bl_rs + bOfs, b_p + bOfs,
            wb_l_ri + wOfs, wb_r_ri + wOfs, bl_ri + bOfs,
            f32_xs, xsb_next,
            xi_tmp, cs, cs2,
            gi_blocks);

        bn_norm<<<bnn_blocks, 256, 0, stream>>>(xi_tmp, cs, cs2,
                                                bn_g + bOfs, bn_b + bOfs,
                                                f32_xi, xib_next, NIi);
    }
}